// Round 15
// baseline (250.402 us; speedup 1.0000x reference)
//
#include <hip/hip_runtime.h>
#include <hip/hip_bf16.h>
#include <stdint.h>

// MHA forward, fp32/bf16 in/out auto-detected, bf16 MFMA internal. MI355X gfx950.
// prep (W transpose, rope tab, x cvt) -> QKV GEMM (gemmt<1>, verified 74us) ->
// flash attn v9 (q-tile 256, dispatch-robust balance) -> O-proj (gemmo4, neutral-ok).
// flash v9 (r15): v7's (y,y+4) big/small pairing balances per-CU work ONLY if flat
//   IDs 256 apart co-locate (round-robin dispatch). Under packed dispatch (adjacent
//   flat IDs same CU), 32 CUs get 2x qt=7 (64 kt-units) vs 32 CUs 2x qt=0 (8) ->
//   ~1.8x makespan. Fix: qt depends on bh parity so BOTH adjacent-bh pairs AND
//   +256-stride pairs are big/small complementary (sum 36 kt). Bijective per bh.
// gemmt QKV: shape-plateaued ~700 TF (8-phase needs 256^2 -> 1.5 rounds, -25% >
//   +10% measured gain at K=1024). r7 1-barrier -33%; r4 grid-quant -16%.
// gemmo4: 128x128 4-wave 2 blk/CU (r14: neutral vs gemmt<0>; kept).

typedef __attribute__((ext_vector_type(8))) short short8;
typedef __attribute__((ext_vector_type(4))) float floatx4;
typedef __attribute__((ext_vector_type(16))) float floatx16;

#define MFMA16(a,b,c) __builtin_amdgcn_mfma_f32_16x16x32_bf16((a),(b),(c),0,0,0)
#define MFMA32(a,b,c) __builtin_amdgcn_mfma_f32_32x32x16_bf16((a),(b),(c),0,0,0)
#define BAR() __builtin_amdgcn_s_barrier()
#define LGKM0 asm volatile("s_waitcnt lgkmcnt(0)" ::: "memory")
#define VMCNT4 asm volatile("s_waitcnt vmcnt(4)" ::: "memory")
#define VMCNT6 asm volatile("s_waitcnt vmcnt(6)" ::: "memory")

__device__ __forceinline__ uint32_t fbits(float f){ uint32_t u; __builtin_memcpy(&u,&f,4); return u; }
__device__ __forceinline__ unsigned short f2bf(float f) {
    uint32_t u = fbits(f);
    return (unsigned short)((u + 0x7fffu + ((u>>16)&1u)) >> 16);
}
__device__ __forceinline__ float bf2f(unsigned short s){ uint32_t u = (uint32_t)s<<16; float f; __builtin_memcpy(&f,&u,4); return f; }
__device__ __forceinline__ uint32_t pkbf(float lo, float hi) {
#if __has_builtin(__builtin_amdgcn_cvt_pk_bf16_f32)
    auto r = __builtin_amdgcn_cvt_pk_bf16_f32(lo, hi);
    uint32_t u; __builtin_memcpy(&u, &r, sizeof(u));
    return u;
#else
    return __builtin_amdgcn_perm(fbits(hi)+0x8000u, fbits(lo)+0x8000u, 0x07060302u);
#endif
}
// raw v_exp_f32: ocml exp2f adds denorm-range fixup ops we never need
__device__ __forceinline__ float fexp2(float x) {
#if __has_builtin(__builtin_amdgcn_exp2f)
    return __builtin_amdgcn_exp2f(x);
#else
    return exp2f(x);
#endif
}

__device__ __forceinline__ void load_lds16(const unsigned short* g, unsigned short* l) {
    __builtin_amdgcn_global_load_lds(
        (const __attribute__((address_space(1))) void*)g,
        (__attribute__((address_space(3))) void*)l, 16, 0, 0);
}

// wave-local dtype sniff: reinterpret first 1024 shorts of x as bf16; fp32 source shows
// huge/NaN patterns in mantissa halves with overwhelming probability.
__device__ __forceinline__ bool sniff_f32(const unsigned short* xr) {
    int lane = threadIdx.x & 63;
    int bad = 0;
#pragma unroll
    for (int i = 0; i < 16; i++) {
        float v = bf2f(xr[lane * 16 + i]);
        if (!(__builtin_fabsf(v) < 1e10f)) bad = 1;
    }
    return __ballot(bad != 0) != 0ull;
}

// ---------------- fused prep: W transposes (blk<4096), rope tab, x convert ----------------
__global__ __launch_bounds__(256) void prep_k(
    const void* __restrict__ x,
    const void* __restrict__ wq, const void* __restrict__ wk,
    const void* __restrict__ wv, const void* __restrict__ wo,
    unsigned short* __restrict__ WT, unsigned short* __restrict__ WoT,
    float2* __restrict__ tab, unsigned short* __restrict__ xb) {
    int blk = blockIdx.x, t = threadIdx.x;
    bool f32 = sniff_f32((const unsigned short*)x);
    if (blk < 4096) {
        __shared__ unsigned short tile[32][33];
        int mat = blk >> 10, r = blk & 1023;
        const void* src = (mat == 0) ? wq : (mat == 1) ? wk : (mat == 2) ? wv : wo;
        unsigned short* dst = (mat < 3) ? (WT + (size_t)mat * 1048576) : WoT;
        int bx = (r & 31) * 32, by = (r >> 5) * 32;
        int tx = t & 31, ty = t >> 5;  // 32 x 8
#pragma unroll
        for (int j = 0; j < 32; j += 8) {
            size_t idx = (size_t)(by + ty + j) * 1024 + bx + tx;
            float v = f32 ? ((const float*)src)[idx] : bf2f(((const unsigned short*)src)[idx]);
            tile[ty + j][tx] = f2bf(v);
        }
        __syncthreads();
#pragma unroll
        for (int j = 0; j < 32; j += 8)
            dst[(size_t)(bx + ty + j) * 1024 + by + tx] = tile[tx][ty + j];
    } else if (blk < 4352) {
        int i = (blk - 4096) * 256 + t;  // 65536 entries
        int pos = i >> 5, j = i & 31;
        float freq = exp2f(-(float)(2 * j) * (1.0f / 64.0f) * 13.287712379549449f);
        float a = (float)pos * freq;
        tab[i] = make_float2(cosf(a), sinf(a));
    } else {
        size_t base = (size_t)(blk - 4352) * 2048 + (size_t)t * 8;
        if (f32) {
            const float4* s4 = (const float4*)((const float*)x + base);
            float4 a = s4[0], b = s4[1];
            uint4 o;
            o.x = pkbf(a.x, a.y); o.y = pkbf(a.z, a.w);
            o.z = pkbf(b.x, b.y); o.w = pkbf(b.z, b.w);
            *(uint4*)(xb + base) = o;
        } else {
            *(uint4*)(xb + base) = *(const uint4*)((const unsigned short*)x + base);
        }
    }
}

// ---------------- gemmt: 128x256 block, 4 waves, per-wave 128x64, BK=32, ring-3 ----------
// MODE 1: QKV (grid 12x64, N=3072): Q(rope,*0.18034), K(rope), V -> (B,H,d,S).
template <int MODE>
__global__ __launch_bounds__(256, 2) void gemmt(
    const unsigned short* __restrict__ A,
    const unsigned short* __restrict__ Bt,
    void* __restrict__ C0,
    unsigned short* __restrict__ C1,
    unsigned short* __restrict__ C2,
    const float2* __restrict__ tab,
    const unsigned short* __restrict__ xsniff) {
    const int K = 1024;
    extern __shared__ __align__(16) char smraw[];
    unsigned short* SL = (unsigned short*)smraw;  // [3][12288]: A at +0, B at +4096

    int t = threadIdx.x;                 // 256 = 4 waves
    int lane = t & 63, w = t >> 6;
    int quad = lane >> 4, l15 = lane & 15;
    int wn = w * 64;

    int nbx = gridDim.x;
    int flat = blockIdx.y * nbx + blockIdx.x;
    int cpx = (nbx * gridDim.y) >> 3;
    int swzid = (flat & 7) * cpx + (flat >> 3);
    int bx = swzid % nbx, by = swzid / nbx;
    int m0 = by * 128, n0 = bx * 256;

    floatx4 acc[8][4];
#pragma unroll
    for (int i = 0; i < 8; i++)
#pragma unroll
        for (int j = 0; j < 4; j++) acc[i][j] = (floatx4){0.f, 0.f, 0.f, 0.f};

    int sg = ((t & 3) ^ ((t >> 3) & 3)) * 8;
    const unsigned short* gA = A + (size_t)(m0 + (t >> 2)) * K + sg;
    const unsigned short* gB = Bt + (size_t)(n0 + (t >> 2)) * K + sg;

    int colsw = (quad ^ ((l15 >> 1) & 3)) * 8;

#pragma unroll
    for (int kt = 0; kt < 2; kt++) {
        unsigned short* Sb = SL + kt * 12288 + w * 512;
        load_lds16(gA + kt * 32, Sb);
        load_lds16(gA + (size_t)64 * K + kt * 32, Sb + 2048);
        load_lds16(gB + kt * 32, Sb + 4096);
        load_lds16(gB + (size_t)64 * K + kt * 32, Sb + 6144);
        load_lds16(gB + (size_t)128 * K + kt * 32, Sb + 8192);
        load_lds16(gB + (size_t)192 * K + kt * 32, Sb + 10240);
    }
    VMCNT6;
    __syncthreads();

    int cur = 0, nxt = 2;
#pragma unroll 1
    for (int kt = 0; kt < 32; kt++) {
        const unsigned short* cA = SL + cur * 12288;
        const unsigned short* cB = SL + cur * 12288 + 4096;
        unsigned short* Sb = SL + nxt * 12288 + w * 512;
        int kc = (kt < 30) ? (kt + 2) : 31;  // clamp: re-stage t31 into dead slot
        size_t ko = (size_t)kc * 32;
        short8 af[4], bf[4];

        // ---- phase 0: m 0..3 x n 0..3; stage A0,A1,B0 of kt+2 ----
#pragma unroll
        for (int m = 0; m < 4; m++)
            af[m] = *(const short8*)(cA + (m * 16 + l15) * 32 + colsw);
#pragma unroll
        for (int n = 0; n < 4; n++)
            bf[n] = *(const short8*)(cB + (wn + n * 16 + l15) * 32 + colsw);
        load_lds16(gA + ko, Sb);
        load_lds16(gA + (size_t)64 * K + ko, Sb + 2048);
        load_lds16(gB + ko, Sb + 4096);
        BAR(); LGKM0;
        __builtin_amdgcn_s_setprio(1);
#pragma unroll
        for (int m = 0; m < 4; m++)
#pragma unroll
            for (int n = 0; n < 4; n++) acc[m][n] = MFMA16(af[m], bf[n], acc[m][n]);
        __builtin_amdgcn_s_setprio(0);
        BAR();

        // ---- phase 1: m 4..7 x n 0..3; stage B1,B2,B3 of kt+2; gate kt+1 ----
#pragma unroll
        for (int m = 0; m < 4; m++)
            af[m] = *(const short8*)(cA + ((m + 4) * 16 + l15) * 32 + colsw);
        load_lds16(gB + (size_t)64 * K + ko, Sb + 6144);
        load_lds16(gB + (size_t)128 * K + ko, Sb + 8192);
        load_lds16(gB + (size_t)192 * K + ko, Sb + 10240);
        BAR(); LGKM0;
        __builtin_amdgcn_s_setprio(1);
#pragma unroll
        for (int m = 0; m < 4; m++)
#pragma unroll
            for (int n = 0; n < 4; n++) acc[m + 4][n] = MFMA16(af[m], bf[n], acc[m + 4][n]);
        __builtin_amdgcn_s_setprio(0);
        VMCNT6;
        BAR();

        cur = (cur == 2) ? 0 : cur + 1;
        nxt = (nxt == 2) ? 0 : nxt + 1;
    }

    // epilogue
    bool out_f32 = (MODE == 0) ? sniff_f32(xsniff) : false;
#pragma unroll
    for (int i = 0; i < 8; i++) {
#pragma unroll
        for (int j = 0; j < 4; j++) {
            int col = n0 + wn + j * 16 + l15;
            int row0 = m0 + i * 16 + quad * 4;
            if (MODE == 0) {
#pragma unroll
                for (int r = 0; r < 4; r++) {
                    size_t idx = (size_t)(row0 + r) * 1024 + col;
                    if (out_f32) ((float*)C0)[idx] = acc[i][j][r];
                    else ((unsigned short*)C0)[idx] = f2bf(acc[i][j][r]);
                }
            } else {
                int which = col >> 10, nn = col & 1023;  // uniform per block
                int b = row0 >> 11, s0 = row0 & 2047;
                if (which == 2) {
                    int hh = nn >> 6, d = nn & 63;
                    uint32_t lo = pkbf(acc[i][j][0], acc[i][j][1]);
                    uint32_t hi = pkbf(acc[i][j][2], acc[i][j][3]);
                    *(uint64_t*)(C2 + ((size_t)((b * 16 + hh) * 64 + d)) * 2048 + s0) =
                        (uint64_t)lo | ((uint64_t)hi << 32);
                } else {
                    int d = nn & 63;
                    unsigned short* dst = (which == 0) ? (unsigned short*)C0 : C1;
                    float sc = (which == 0) ? 0.18033688011112042f : 1.0f;  // 0.125*log2(e)
#pragma unroll
                    for (int r = 0; r < 4; r++) {
                        int s = s0 + r;
                        float v = acc[i][j][r];
                        float pv = __shfl_xor(v, 1);
                        float2 cs = tab[(s << 5) + (d >> 1)];
                        float o = (d & 1) ? (v * cs.x + pv * cs.y) : (v * cs.x - pv * cs.y);
                        dst[((size_t)(b * 2048 + s)) * 1024 + nn] = f2bf(o * sc);
                    }
                }
            }
        }
    }
}

// ---------------- gemmo4: O-proj, 128x128 block, 4 waves (2Mx2N), 2 blk/CU -----------
__global__ __launch_bounds__(256, 2) void gemmo4(
    const unsigned short* __restrict__ A,
    const unsigned short* __restrict__ Bt,
    void* __restrict__ C0,
    const unsigned short* __restrict__ xsniff) {
    const int K = 1024;
    extern __shared__ __align__(16) char smraw[];
    unsigned short* SL = (unsigned short*)smraw;  // [3][8192]: A at +0, B at +4096

    int t = threadIdx.x;                 // 256 = 4 waves
    int lane = t & 63, w = t >> 6;
    int quad = lane >> 4, l15 = lane & 15;
    int wm = (w >> 1) * 64, wn = (w & 1) * 64;  // 2Mx2N wave grid, 64x64 each

    int nbx = gridDim.x;                 // 8
    int flat = blockIdx.y * nbx + blockIdx.x;
    int cpx = (nbx * gridDim.y) >> 3;    // 64
    int swzid = (flat & 7) * cpx + (flat >> 3);
    int bx = swzid % nbx, by = swzid / nbx;
    int m0 = by * 128, n0 = bx * 128;

    floatx4 acc[4][4];
#pragma unroll
    for (int i = 0; i < 4; i++)
#pragma unroll
        for (int j = 0; j < 4; j++) acc[i][j] = (floatx4){0.f, 0.f, 0.f, 0.f};

    int sg = ((t & 3) ^ ((t >> 3) & 3)) * 8;
    const unsigned short* gA = A + (size_t)(m0 + (t >> 2)) * K + sg;
    const unsigned short* gB = Bt + (size_t)(n0 + (t >> 2)) * K + sg;

    int colsw = (quad ^ ((l15 >> 1) & 3)) * 8;

#pragma unroll
    for (int kt = 0; kt < 2; kt++) {
        unsigned short* Sb = SL + kt * 8192 + w * 512;
        load_lds16(gA + kt * 32, Sb);
        load_lds16(gA + (size_t)64 * K + kt * 32, Sb + 2048);
        load_lds16(gB + kt * 32, Sb + 4096);
        load_lds16(gB + (size_t)64 * K + kt * 32, Sb + 6144);
    }
    VMCNT4;
    __syncthreads();

    int cur = 0, nxt = 2;
#pragma unroll 1
    for (int kt = 0; kt < 32; kt++) {
        const unsigned short* cA = SL + cur * 8192;
        const unsigned short* cB = SL + cur * 8192 + 4096;
        unsigned short* Sb = SL + nxt * 8192 + w * 512;
        int kc = (kt < 30) ? (kt + 2) : 31;
        size_t ko = (size_t)kc * 32;
        short8 af[2], bf[4];

        // ---- phase 0: m 0..1 x n 0..3; stage A0,A1 of kt+2 ----
#pragma unroll
        for (int m = 0; m < 2; m++)
            af[m] = *(const short8*)(cA + ((wm + m * 16 + l15)) * 32 + colsw);
#pragma unroll
        for (int n = 0; n < 4; n++)
            bf[n] = *(const short8*)(cB + ((wn + n * 16 + l15)) * 32 + colsw);
        load_lds16(gA + ko, Sb);
        load_lds16(gA + (size_t)64 * K + ko, Sb + 2048);
        BAR(); LGKM0;
        __builtin_amdgcn_s_setprio(1);
#pragma unroll
        for (int m = 0; m < 2; m++)
#pragma unroll
            for (int n = 0; n < 4; n++) acc[m][n] = MFMA16(af[m], bf[n], acc[m][n]);
        __builtin_amdgcn_s_setprio(0);
        BAR();

        // ---- phase 1: m 2..3 x n 0..3; stage B0,B1 of kt+2; gate kt+1 ----
#pragma unroll
        for (int m = 0; m < 2; m++)
            af[m] = *(const short8*)(cA + ((wm + (m + 2) * 16 + l15)) * 32 + colsw);
        load_lds16(gB + ko, Sb + 4096);
        load_lds16(gB + (size_t)64 * K + ko, Sb + 6144);
        BAR(); LGKM0;
        __builtin_amdgcn_s_setprio(1);
#pragma unroll
        for (int m = 0; m < 2; m++)
#pragma unroll
            for (int n = 0; n < 4; n++) acc[m + 2][n] = MFMA16(af[m], bf[n], acc[m + 2][n]);
        __builtin_amdgcn_s_setprio(0);
        VMCNT4;
        BAR();

        cur = (cur == 2) ? 0 : cur + 1;
        nxt = (nxt == 2) ? 0 : nxt + 1;
    }

    bool out_f32 = sniff_f32(xsniff);
#pragma unroll
    for (int i = 0; i < 4; i++) {
#pragma unroll
        for (int j = 0; j < 4; j++) {
            int col = n0 + wn + j * 16 + l15;
            int row0 = m0 + wm + i * 16 + quad * 4;
#pragma unroll
            for (int r = 0; r < 4; r++) {
                size_t idx = (size_t)(row0 + r) * 1024 + col;
                if (out_f32) ((float*)C0)[idx] = acc[i][j][r];
                else ((unsigned short*)C0)[idx] = f2bf(acc[i][j][r]);
            }
        }
    }
}

// ---------------- flash attention v9: q-tile 256, dispatch-robust load balance -------------
// grid (64, 8): 512 blocks, 2/CU. qt mapping depends on bh parity so that BOTH
// plausible co-residency pairings are big/small complementary (sum = 36 kt):
//  - packed dispatch: adjacent flat IDs (same y, bh and bh+1) -> opposite parity
//  - round-robin: flat IDs 256 apart (y and y+4, same bh) -> complementary within parity
// Bijective per bh: even bh {7,6,5,4,0,1,2,3}; odd bh {0,1,2,3,7,6,5,4}.
__global__ __launch_bounds__(512, 4) void flash_k(
    const unsigned short* __restrict__ Qb,
    const unsigned short* __restrict__ Kb,
    const unsigned short* __restrict__ Vt,   // (B,H,64,S)
    unsigned short* __restrict__ A2) {
    __shared__ __align__(16) unsigned short Kl[2][64 * 64];  // [kv][d] swizzled
    __shared__ __align__(16) unsigned short Vl[2][64 * 64];  // [d][kv] swizzled

    int bh = blockIdx.x;
    int y = blockIdx.y;
    int qt = (bh & 1) ? ((y < 4) ? y : (11 - y))
                      : ((y < 4) ? (7 - y) : (y - 4));
    int b = bh >> 4, h = bh & 15;
    int t = threadIdx.x, lane = t & 63, w = t >> 6;  // w 0..7
    int l31 = lane & 31, half = lane >> 5;
    size_t base = ((size_t)b * 2048) * 1024 + h * 64;
    int q0w = qt * 256 + w * 32;

    short8 Qf[4];
#pragma unroll
    for (int ks = 0; ks < 4; ks++)
        Qf[ks] = *(const short8*)(Qb + base + (size_t)(q0w + l31) * 1024 + ks * 16 + half * 8);

    floatx16 O[2];
    O[0] = (floatx16)0.0f; O[1] = (floatx16)0.0f;
    float lsum = 0.f;

    int nk = 4 * (qt + 1);

    int srow = t >> 3, gs = t & 7;
    const unsigned short* kg = Kb + base + (size_t)srow * 1024 + gs * 8;
    const unsigned short* vg = Vt + ((size_t)(bh * 64 + srow)) * 2048 + gs * 8;
    int sw = srow * 64 + ((gs ^ (srow & 7)) * 8);

    short8 rk = *(const short8*)(kg);
    short8 rv = *(const short8*)(vg);

    for (int kt = 0; kt < nk; kt++) {
        int k0 = kt * 64, bf = kt & 1;
        *(short8*)&Kl[bf][sw] = rk;
        *(short8*)&Vl[bf][sw] = rv;
        __syncthreads();
        if (kt + 1 < nk) {
            size_t ko = (size_t)(kt + 1) * 64;
            rk = *(const short8*)(kg + ko * 1024);
            rv = *(const short8*)(vg + ko);
        }
#pragma unroll
        for (int mb = 0; mb < 2; mb++) {
            int k0mb = k0 + mb * 32;
            if (k0mb >= q0w + 32) continue;  // fully-masked 32-row band
            short8 Ka[4];
#pragma unroll
            for (int ks = 0; ks < 4; ks++)
                Ka[ks] = *(const short8*)&Kl[bf][(mb * 32 + l31) * 64 +
                                                 (((ks * 2 + half) ^ (l31 & 7)) * 8)];
            floatx16 Sc = (floatx16)0.0f;
#pragma unroll
            for (int ks = 0; ks < 4; ks++)
                Sc = MFMA32(Ka[ks], Qf[ks], Sc);

            bool domask = (k0mb + 31 > q0w);
            int thr = q0w + l31 - k0mb - half * 4;  // mask elem iff C_e > thr
            float p[16];
#pragma unroll
            for (int e = 0; e < 16; e++) {
                float v = fexp2(Sc[e]);
                if (domask) {
                    const int ce = (e & 3) + ((e >> 2) << 3);
                    v = (ce > thr) ? 0.f : v;
                }
                p[e] = v;
            }
            float t0 = (p[0] + p[1]) + (p[2] + p[3]);
            float t1 = (p[4] + p[5]) + (p[6] + p[7]);
            float t2 = (p[8] + p[9]) + (p[10] + p[11]);
            float t3 = (p[12] + p[13]) + (p[14] + p[15]);
            lsum += (t0 + t1) + (t2 + t3);
            uint32_t pkm[8];
#pragma unroll
            for (int jj = 0; jj < 8; jj++)
                pkm[jj] = pkbf(p[2 * jj], p[2 * jj + 1]);

            short8 Va[2][2];  // [db][ks2]
#pragma unroll
            for (int db = 0; db < 2; db++)
#pragma unroll
                for (int ks2 = 0; ks2 < 2; ks2++)
                    Va[db][ks2] = *(const short8*)&Vl[bf][(db * 32 + l31) * 64 +
                                                         ((((mb * 2 + ks2) * 2 + half) ^ (l31 & 7)) * 8)];
#pragma unroll
            for (int ks2 = 0; ks2 < 2; ks2++) {
                uint32_t p0 = pkm[4 * ks2 + 0];
                uint32_t p1 = pkm[4 * ks2 + 1];
                uint32_t p2 = pkm[4 * ks2 + 2];
                uint32_t p3 = pkm[4 * ks2 + 3];
                uint32_t u = half ? p0 : p2;
                uint32_t v2 = half ? p1 : p3;
                uint32_t ya = (uint32_t)__shfl_xor((int)u, 32);
                uint32_t yb = (uint32_t)__shfl_xor((int)v2, 32);
                union { short8 s; uint32_t q[4]; } bb;
                bb.q[0] = half ? ya : p0;
                bb.q[1] = half ? yb : p1;
                bb.q[2] = half ? p2 : ya;
                bb.q[3] = half ? p3 : yb;
#pragma unroll
                for (int db = 0; db < 2; db++)
                    O[db] = MFMA32(Va[db][ks2], bb.s, O[db]);
            }
        }
    }

    float tot = lsum + __shfl_xor(lsum, 32);
    float inv = 1.0f / tot;
    int scol = q0w + l31;
    unsigned short* op = A2 + base + (size_t)scol * 1024;
#pragma unroll
    for (int db = 0; db < 2; db++) {
#pragma unroll
        for (int g = 0; g < 4; g++) {
            int d0 = db * 32 + half * 4 + g * 8;
            float v0 = O[db][g * 4 + 0] * inv;
            float v1 = O[db][g * 4 + 1] * inv;
            float v2 = O[db][g * 4 + 2] * inv;
            float v3 = O[db][g * 4 + 3] * inv;
            uint32_t lo = pkbf(v0, v1), hi = pkbf(v2, v3);
            *(uint64_t*)(op + d0) = (uint64_t)lo | ((uint64_t)hi << 32);
        }
    }
}

extern "C" void kernel_launch(void* const* d_in, const int* in_sizes, int n_in,
                              void* d_out, int out_size, void* d_ws, size_t ws_size,
                              hipStream_t stream) {
    const void* x  = d_in[0];
    const void* wq = d_in[1];
    const void* wk = d_in[2];
    const void* wv = d_in[3];
    const void* wo = d_in[4];

    char* ws = (char*)d_ws;
    unsigned short* WT  = (unsigned short*)(ws);                        // 3x1024x1024 bf16
    unsigned short* WoT = (unsigned short*)(ws + 6291456);              // 1024x1024 bf16
    float2*         tab = (float2*)(ws + 8388608);                      // 2048x32 float2
    unsigned short* xb  = (unsigned short*)(ws + 8913920);              // 16 MB bf16 x
    unsigned short* Qb  = (unsigned short*)(ws + 8913920 + 16777216ull);
    unsigned short* Kb  = (unsigned short*)(ws + 8913920 + 2ull * 16777216);
    unsigned short* Vt  = (unsigned short*)(ws + 8913920 + 3ull * 16777216);  // (B,H,64,S)
    unsigned short* A2  = xb;  // alias: xb dead after QKV GEMM

    (void)hipFuncSetAttribute(reinterpret_cast<const void*>(gemmt<1>),
                              hipFuncAttributeMaxDynamicSharedMemorySize, 73728);
    (void)hipFuncSetAttribute(reinterpret_cast<const void*>(gemmo4),
                              hipFuncAttributeMaxDynamicSharedMemorySize, 49152);

    prep_k<<<8448, 256, 0, stream>>>(x, wq, wk, wv, wo, WT, WoT, tab, xb);

    gemmt<1><<<dim3(12, 64), 256, 73728, stream>>>(xb, WT, Qb, Kb, Vt, tab,
                                                   (const unsigned short*)x);
    flash_k<<<dim3(64, 8), 512, 0, stream>>>(Qb, Kb, Vt, A2);
    gemmo4<<<dim3(8, 64), 256, 49152, stream>>>(A2, WoT, d_out,
                                                (const unsigned short*)x);
}

// Round 16
// 244.600 us; speedup vs baseline: 1.0237x; 1.0237x over previous
//
#include <hip/hip_runtime.h>
#include <hip/hip_bf16.h>
#include <stdint.h>

// MHA forward, fp32/bf16 in/out auto-detected, bf16 MFMA internal. MI355X gfx950.
// prep (W transpose, rope tab, x cvt) -> QKV GEMM (gemmt<1>) -> flash attn v7
// (q-tile 256, KVBLK=64) -> O-proj GEMM (gemmt<0>).
// FINAL: the r13-verified best build (246.66us). Session probe ledger:
//  - QKV: 2-phase ring-3 @ ~700 TF is family optimum (1-barrier -33% r7, 256^2
//    grid-quant -16% r4, 64x64-waves -6% r3). 8-phase shape-blocked: 256^2 tile ->
//    grid 384 = 1.5 CU rounds (-25%) > +10% measured 8-phase gain at K=1024.
//  - flash: q-tile 256 verified +7us (r10); KVBLK=128 -8 (r12), kv-band splits
//    regress/spill (r2), bh-parity balance null (r15).
//  - O-proj: gemmt<0> == gemmo4 within noise (r14) -> not a material term.
//  - (512,6) launch-bounds spill lesson (r2): FETCH x9 signature.
// gemmt: 128x256, 4 waves, per-wave 128x64, BK=32, ring-3 72KB (2 blk/CU),
//   counted vmcnt(6), slot^=(row>>1)&3 swizzle both sides, 0 bank conflicts.
// flash v7: 8 waves x 32 q-cols over full kv; (64,8) grid, (y,y+4) big/small pair.

typedef __attribute__((ext_vector_type(8))) short short8;
typedef __attribute__((ext_vector_type(4))) float floatx4;
typedef __attribute__((ext_vector_type(16))) float floatx16;

#define MFMA16(a,b,c) __builtin_amdgcn_mfma_f32_16x16x32_bf16((a),(b),(c),0,0,0)
#define MFMA32(a,b,c) __builtin_amdgcn_mfma_f32_32x32x16_bf16((a),(b),(c),0,0,0)
#define BAR() __builtin_amdgcn_s_barrier()
#define LGKM0 asm volatile("s_waitcnt lgkmcnt(0)" ::: "memory")
#define VMCNT6 asm volatile("s_waitcnt vmcnt(6)" ::: "memory")

__device__ __forceinline__ uint32_t fbits(float f){ uint32_t u; __builtin_memcpy(&u,&f,4); return u; }
__device__ __forceinline__ unsigned short f2bf(float f) {
    uint32_t u = fbits(f);
    return (unsigned short)((u + 0x7fffu + ((u>>16)&1u)) >> 16);
}
__device__ __forceinline__ float bf2f(unsigned short s){ uint32_t u = (uint32_t)s<<16; float f; __builtin_memcpy(&f,&u,4); return f; }
__device__ __forceinline__ uint32_t pkbf(float lo, float hi) {
#if __has_builtin(__builtin_amdgcn_cvt_pk_bf16_f32)
    auto r = __builtin_amdgcn_cvt_pk_bf16_f32(lo, hi);
    uint32_t u; __builtin_memcpy(&u, &r, sizeof(u));
    return u;
#else
    return __builtin_amdgcn_perm(fbits(hi)+0x8000u, fbits(lo)+0x8000u, 0x07060302u);
#endif
}
// raw v_exp_f32: ocml exp2f adds denorm-range fixup ops we never need
__device__ __forceinline__ float fexp2(float x) {
#if __has_builtin(__builtin_amdgcn_exp2f)
    return __builtin_amdgcn_exp2f(x);
#else
    return exp2f(x);
#endif
}

__device__ __forceinline__ void load_lds16(const unsigned short* g, unsigned short* l) {
    __builtin_amdgcn_global_load_lds(
        (const __attribute__((address_space(1))) void*)g,
        (__attribute__((address_space(3))) void*)l, 16, 0, 0);
}

// wave-local dtype sniff: reinterpret first 1024 shorts of x as bf16; fp32 source shows
// huge/NaN patterns in mantissa halves with overwhelming probability.
__device__ __forceinline__ bool sniff_f32(const unsigned short* xr) {
    int lane = threadIdx.x & 63;
    int bad = 0;
#pragma unroll
    for (int i = 0; i < 16; i++) {
        float v = bf2f(xr[lane * 16 + i]);
        if (!(__builtin_fabsf(v) < 1e10f)) bad = 1;
    }
    return __ballot(bad != 0) != 0ull;
}

// ---------------- fused prep: W transposes (blk<4096), rope tab, x convert ----------------
__global__ __launch_bounds__(256) void prep_k(
    const void* __restrict__ x,
    const void* __restrict__ wq, const void* __restrict__ wk,
    const void* __restrict__ wv, const void* __restrict__ wo,
    unsigned short* __restrict__ WT, unsigned short* __restrict__ WoT,
    float2* __restrict__ tab, unsigned short* __restrict__ xb) {
    int blk = blockIdx.x, t = threadIdx.x;
    bool f32 = sniff_f32((const unsigned short*)x);
    if (blk < 4096) {
        __shared__ unsigned short tile[32][33];
        int mat = blk >> 10, r = blk & 1023;
        const void* src = (mat == 0) ? wq : (mat == 1) ? wk : (mat == 2) ? wv : wo;
        unsigned short* dst = (mat < 3) ? (WT + (size_t)mat * 1048576) : WoT;
        int bx = (r & 31) * 32, by = (r >> 5) * 32;
        int tx = t & 31, ty = t >> 5;  // 32 x 8
#pragma unroll
        for (int j = 0; j < 32; j += 8) {
            size_t idx = (size_t)(by + ty + j) * 1024 + bx + tx;
            float v = f32 ? ((const float*)src)[idx] : bf2f(((const unsigned short*)src)[idx]);
            tile[ty + j][tx] = f2bf(v);
        }
        __syncthreads();
#pragma unroll
        for (int j = 0; j < 32; j += 8)
            dst[(size_t)(bx + ty + j) * 1024 + by + tx] = tile[tx][ty + j];
    } else if (blk < 4352) {
        int i = (blk - 4096) * 256 + t;  // 65536 entries
        int pos = i >> 5, j = i & 31;
        float freq = exp2f(-(float)(2 * j) * (1.0f / 64.0f) * 13.287712379549449f);
        float a = (float)pos * freq;
        tab[i] = make_float2(cosf(a), sinf(a));
    } else {
        size_t base = (size_t)(blk - 4352) * 2048 + (size_t)t * 8;
        if (f32) {
            const float4* s4 = (const float4*)((const float*)x + base);
            float4 a = s4[0], b = s4[1];
            uint4 o;
            o.x = pkbf(a.x, a.y); o.y = pkbf(a.z, a.w);
            o.z = pkbf(b.x, b.y); o.w = pkbf(b.z, b.w);
            *(uint4*)(xb + base) = o;
        } else {
            *(uint4*)(xb + base) = *(const uint4*)((const unsigned short*)x + base);
        }
    }
}

// ---------------- gemmt: 128x256 block, 4 waves, per-wave 128x64, BK=32, ring-3 ----------
// C = A * W (Bt = W^T). MODE 1: QKV (grid 12x64, N=3072): Q(rope,*0.18034), K(rope),
// V -> (B,H,d,S). MODE 0: O-proj (grid 4x64, N=1024) -> d_out fp32/bf16 per sniff.
// Per kt two phase-pairs {ds_reads; 3 stage loads; BAR; LGKM0; 16 MFMA; BAR},
// counted VMCNT6 once per kt (kt+2's 6 loads stay in flight across the barrier).
// Swizzle: 16B-slot ^= (row>>1)&3 on global source (linear gload_lds dest, rule 21)
// + on ds_read col. 0 bank conflicts (PMC-verified).
template <int MODE>
__global__ __launch_bounds__(256, 2) void gemmt(
    const unsigned short* __restrict__ A,
    const unsigned short* __restrict__ Bt,
    void* __restrict__ C0,
    unsigned short* __restrict__ C1,
    unsigned short* __restrict__ C2,
    const float2* __restrict__ tab,
    const unsigned short* __restrict__ xsniff) {
    const int K = 1024;
    extern __shared__ __align__(16) char smraw[];
    unsigned short* SL = (unsigned short*)smraw;  // [3][12288]: A at +0, B at +4096

    int t = threadIdx.x;                 // 256 = 4 waves
    int lane = t & 63, w = t >> 6;
    int quad = lane >> 4, l15 = lane & 15;
    int wn = w * 64;                     // 1M x 4N: wave owns cols [wn, wn+64), all 128 rows

    // bijective XCD swizzle (nwg % 8 == 0 for both grids)
    int nbx = gridDim.x;
    int flat = blockIdx.y * nbx + blockIdx.x;
    int cpx = (nbx * gridDim.y) >> 3;
    int swzid = (flat & 7) * cpx + (flat >> 3);
    int bx = swzid % nbx, by = swzid / nbx;
    int m0 = by * 128, n0 = bx * 256;

    floatx4 acc[8][4];
#pragma unroll
    for (int i = 0; i < 8; i++)
#pragma unroll
        for (int j = 0; j < 4; j++) acc[i][j] = (floatx4){0.f, 0.f, 0.f, 0.f};

    // staging: thread t -> row = t>>2 (64 rows per 4KB load), 16B slot = t&3;
    // global source slot pre-swizzled: (t&3) ^ ((row>>1)&3) = (t&3) ^ ((t>>3)&3)
    int sg = ((t & 3) ^ ((t >> 3) & 3)) * 8;
    const unsigned short* gA = A + (size_t)(m0 + (t >> 2)) * K + sg;
    const unsigned short* gB = Bt + (size_t)(n0 + (t >> 2)) * K + sg;

    // read swizzle: col 16B-slot = quad ^ ((l15>>1)&3)
    int colsw = (quad ^ ((l15 >> 1) & 3)) * 8;

    // prologue: stage kt0 -> slot0, kt1 -> slot1 (12 loads), keep kt1's 6 in flight
#pragma unroll
    for (int kt = 0; kt < 2; kt++) {
        unsigned short* Sb = SL + kt * 12288 + w * 512;
        load_lds16(gA + kt * 32, Sb);
        load_lds16(gA + (size_t)64 * K + kt * 32, Sb + 2048);
        load_lds16(gB + kt * 32, Sb + 4096);
        load_lds16(gB + (size_t)64 * K + kt * 32, Sb + 6144);
        load_lds16(gB + (size_t)128 * K + kt * 32, Sb + 8192);
        load_lds16(gB + (size_t)192 * K + kt * 32, Sb + 10240);
    }
    VMCNT6;
    __syncthreads();

    int cur = 0, nxt = 2;
#pragma unroll 1
    for (int kt = 0; kt < 32; kt++) {
        const unsigned short* cA = SL + cur * 12288;
        const unsigned short* cB = SL + cur * 12288 + 4096;
        unsigned short* Sb = SL + nxt * 12288 + w * 512;
        int kc = (kt < 30) ? (kt + 2) : 31;  // clamp: re-stage t31 into dead slot
        size_t ko = (size_t)kc * 32;
        short8 af[4], bf[4];

        // ---- phase 0: m 0..3 x n 0..3; stage A0,A1,B0 of kt+2 ----
#pragma unroll
        for (int m = 0; m < 4; m++)
            af[m] = *(const short8*)(cA + (m * 16 + l15) * 32 + colsw);
#pragma unroll
        for (int n = 0; n < 4; n++)
            bf[n] = *(const short8*)(cB + (wn + n * 16 + l15) * 32 + colsw);
        load_lds16(gA + ko, Sb);
        load_lds16(gA + (size_t)64 * K + ko, Sb + 2048);
        load_lds16(gB + ko, Sb + 4096);
        BAR(); LGKM0;
        __builtin_amdgcn_s_setprio(1);
#pragma unroll
        for (int m = 0; m < 4; m++)
#pragma unroll
            for (int n = 0; n < 4; n++) acc[m][n] = MFMA16(af[m], bf[n], acc[m][n]);
        __builtin_amdgcn_s_setprio(0);
        BAR();

        // ---- phase 1: m 4..7 x n 0..3; stage B1,B2,B3 of kt+2; gate kt+1 ----
#pragma unroll
        for (int m = 0; m < 4; m++)
            af[m] = *(const short8*)(cA + ((m + 4) * 16 + l15) * 32 + colsw);
        load_lds16(gB + (size_t)64 * K + ko, Sb + 6144);
        load_lds16(gB + (size_t)128 * K + ko, Sb + 8192);
        load_lds16(gB + (size_t)192 * K + ko, Sb + 10240);
        BAR(); LGKM0;
        __builtin_amdgcn_s_setprio(1);
#pragma unroll
        for (int m = 0; m < 4; m++)
#pragma unroll
            for (int n = 0; n < 4; n++) acc[m + 4][n] = MFMA16(af[m], bf[n], acc[m + 4][n]);
        __builtin_amdgcn_s_setprio(0);
        VMCNT6;
        BAR();

        cur = (cur == 2) ? 0 : cur + 1;
        nxt = (nxt == 2) ? 0 : nxt + 1;
    }

    // epilogue
    bool out_f32 = (MODE == 0) ? sniff_f32(xsniff) : false;
#pragma unroll
    for (int i = 0; i < 8; i++) {
#pragma unroll
        for (int j = 0; j < 4; j++) {
            int col = n0 + wn + j * 16 + l15;
            int row0 = m0 + i * 16 + quad * 4;
            if (MODE == 0) {
#pragma unroll
                for (int r = 0; r < 4; r++) {
                    size_t idx = (size_t)(row0 + r) * 1024 + col;
                    if (out_f32) ((float*)C0)[idx] = acc[i][j][r];
                    else ((unsigned short*)C0)[idx] = f2bf(acc[i][j][r]);
                }
            } else {
                int which = col >> 10, nn = col & 1023;  // uniform per block
                int b = row0 >> 11, s0 = row0 & 2047;
                if (which == 2) {
                    int hh = nn >> 6, d = nn & 63;
                    uint32_t lo = pkbf(acc[i][j][0], acc[i][j][1]);
                    uint32_t hi = pkbf(acc[i][j][2], acc[i][j][3]);
                    *(uint64_t*)(C2 + ((size_t)((b * 16 + hh) * 64 + d)) * 2048 + s0) =
                        (uint64_t)lo | ((uint64_t)hi << 32);
                } else {
                    int d = nn & 63;
                    unsigned short* dst = (which == 0) ? (unsigned short*)C0 : C1;
                    float sc = (which == 0) ? 0.18033688011112042f : 1.0f;  // 0.125*log2(e)
#pragma unroll
                    for (int r = 0; r < 4; r++) {
                        int s = s0 + r;
                        float v = acc[i][j][r];
                        float pv = __shfl_xor(v, 1);
                        float2 cs = tab[(s << 5) + (d >> 1)];
                        float o = (d & 1) ? (v * cs.x + pv * cs.y) : (v * cs.x - pv * cs.y);
                        dst[((size_t)(b * 2048 + s)) * 1024 + nn] = f2bf(o * sc);
                    }
                }
            }
        }
    }
}

// ---------------- flash attention v7: q-tile 256, 8 q-waves, 2 band-units/kt ----------------
// grid (64, 8): x = b*16+h; y -> q-tile, big-first pairing (y,y+4) -> (7-y, y-4):
// every CU gets exactly 72 band-units. 512 thr = 8 waves, wave w owns q cols
// [qt*256+w*32, +32) over the FULL kv range (no combine). Halves K/V L2/L3 traffic
// vs q-tile 128 (278->147MB). Inner body = v4's verified mb-loop; v6's staging.
__global__ __launch_bounds__(512, 4) void flash_k(
    const unsigned short* __restrict__ Qb,
    const unsigned short* __restrict__ Kb,
    const unsigned short* __restrict__ Vt,   // (B,H,64,S)
    unsigned short* __restrict__ A2) {
    __shared__ __align__(16) unsigned short Kl[2][64 * 64];  // [kv][d] swizzled
    __shared__ __align__(16) unsigned short Vl[2][64 * 64];  // [d][kv] swizzled

    int bh = blockIdx.x;
    int y = blockIdx.y;
    int qt = (y < 4) ? (7 - y) : (y - 4);  // big tiles first; (y,y+4) pair = 72 units
    int b = bh >> 4, h = bh & 15;
    int t = threadIdx.x, lane = t & 63, w = t >> 6;  // w 0..7
    int l31 = lane & 31, half = lane >> 5;
    size_t base = ((size_t)b * 2048) * 1024 + h * 64;
    int q0w = qt * 256 + w * 32;

    // resident Q^T B-fragments [ks]
    short8 Qf[4];
#pragma unroll
    for (int ks = 0; ks < 4; ks++)
        Qf[ks] = *(const short8*)(Qb + base + (size_t)(q0w + l31) * 1024 + ks * 16 + half * 8);

    floatx16 O[2];
    O[0] = (floatx16)0.0f; O[1] = (floatx16)0.0f;
    float lsum = 0.f;

    int nk = 4 * (qt + 1);

    // staging: 512 threads, 1 short8 of K and 1 of V each; row = t>>3, 16B slot = t&7
    int srow = t >> 3, gs = t & 7;
    const unsigned short* kg = Kb + base + (size_t)srow * 1024 + gs * 8;
    const unsigned short* vg = Vt + ((size_t)(bh * 64 + srow)) * 2048 + gs * 8;
    int sw = srow * 64 + ((gs ^ (srow & 7)) * 8);

    short8 rk = *(const short8*)(kg);
    short8 rv = *(const short8*)(vg);

    for (int kt = 0; kt < nk; kt++) {
        int k0 = kt * 64, bf = kt & 1;
        *(short8*)&Kl[bf][sw] = rk;
        *(short8*)&Vl[bf][sw] = rv;
        __syncthreads();
        if (kt + 1 < nk) {
            size_t ko = (size_t)(kt + 1) * 64;
            rk = *(const short8*)(kg + ko * 1024);
            rv = *(const short8*)(vg + ko);
        }
#pragma unroll
        for (int mb = 0; mb < 2; mb++) {
            int k0mb = k0 + mb * 32;
            if (k0mb >= q0w + 32) continue;  // fully-masked 32-row band
            short8 Ka[4];
#pragma unroll
            for (int ks = 0; ks < 4; ks++)
                Ka[ks] = *(const short8*)&Kl[bf][(mb * 32 + l31) * 64 +
                                                 (((ks * 2 + half) ^ (l31 & 7)) * 8)];
            floatx16 Sc = (floatx16)0.0f;
#pragma unroll
            for (int ks = 0; ks < 4; ks++)
                Sc = MFMA32(Ka[ks], Qf[ks], Sc);

            bool domask = (k0mb + 31 > q0w);
            int thr = q0w + l31 - k0mb - half * 4;  // mask elem iff C_e > thr
            float p[16];
#pragma unroll
            for (int e = 0; e < 16; e++) {
                float v = fexp2(Sc[e]);
                if (domask) {
                    const int ce = (e & 3) + ((e >> 2) << 3);
                    v = (ce > thr) ? 0.f : v;
                }
                p[e] = v;
            }
            float t0 = (p[0] + p[1]) + (p[2] + p[3]);
            float t1 = (p[4] + p[5]) + (p[6] + p[7]);
            float t2 = (p[8] + p[9]) + (p[10] + p[11]);
            float t3 = (p[12] + p[13]) + (p[14] + p[15]);
            lsum += (t0 + t1) + (t2 + t3);
            uint32_t pkm[8];
#pragma unroll
            for (int jj = 0; jj < 8; jj++)
                pkm[jj] = pkbf(p[2 * jj], p[2 * jj + 1]);

            short8 Va[2][2];  // [db][ks2]
#pragma unroll
            for (int db = 0; db < 2; db++)
#pragma unroll
                for (int ks2 = 0; ks2 < 2; ks2++)
                    Va[db][ks2] = *(const short8*)&Vl[bf][(db * 32 + l31) * 64 +
                                                         ((((mb * 2 + ks2) * 2 + half) ^ (l31 & 7)) * 8)];
#pragma unroll
            for (int ks2 = 0; ks2 < 2; ks2++) {
                uint32_t p0 = pkm[4 * ks2 + 0];
                uint32_t p1 = pkm[4 * ks2 + 1];
                uint32_t p2 = pkm[4 * ks2 + 2];
                uint32_t p3 = pkm[4 * ks2 + 3];
                uint32_t u = half ? p0 : p2;
                uint32_t v2 = half ? p1 : p3;
                uint32_t ya = (uint32_t)__shfl_xor((int)u, 32);
                uint32_t yb = (uint32_t)__shfl_xor((int)v2, 32);
                union { short8 s; uint32_t q[4]; } bb;
                bb.q[0] = half ? ya : p0;
                bb.q[1] = half ? yb : p1;
                bb.q[2] = half ? p2 : ya;
                bb.q[3] = half ? p3 : yb;
#pragma unroll
                for (int db = 0; db < 2; db++)
                    O[db] = MFMA32(Va[db][ks2], bb.s, O[db]);
            }
        }
    }

    float tot = lsum + __shfl_xor(lsum, 32);
    float inv = 1.0f / tot;
    int scol = q0w + l31;
    unsigned short* op = A2 + base + (size_t)scol * 1024;
#pragma unroll
    for (int db = 0; db < 2; db++) {
#pragma unroll
        for (int g = 0; g < 4; g++) {
            int d0 = db * 32 + half * 4 + g * 8;
            float v0 = O[db][g * 4 + 0] * inv;
            float v1 = O[db][g * 4 + 1] * inv;
            float v2 = O[db][g * 4 + 2] * inv;
            float v3 = O[db][g * 4 + 3] * inv;
            uint32_t lo = pkbf(v0, v1), hi = pkbf(v2, v3);
            *(uint64_t*)(op + d0) = (uint64_t)lo | ((uint64_t)hi << 32);
        }
    }
}

extern "C" void kernel_launch(void* const* d_in, const int* in_sizes, int n_in,
                              void* d_out, int out_size, void* d_ws, size_t ws_size,
                              hipStream_t stream) {
    const void* x  = d_in[0];
    const void* wq = d_in[1];
    const void* wk = d_in[2];
    const void* wv = d_in[3];
    const void* wo = d_in[4];

    char* ws = (char*)d_ws;
    unsigned short* WT  = (unsigned short*)(ws);                        // 3x1024x1024 bf16
    unsigned short* WoT = (unsigned short*)(ws + 6291456);              // 1024x1024 bf16
    float2*         tab = (float2*)(ws + 8388608);                      // 2048x32 float2
    unsigned short* xb  = (unsigned short*)(ws + 8913920);              // 16 MB bf16 x
    unsigned short* Qb  = (unsigned short*)(ws + 8913920 + 16777216ull);
    unsigned short* Kb  = (unsigned short*)(ws + 8913920 + 2ull * 16777216);
    unsigned short* Vt  = (unsigned short*)(ws + 8913920 + 3ull * 16777216);  // (B,H,64,S)
    unsigned short* A2  = xb;  // alias: xb dead after QKV GEMM

    (void)hipFuncSetAttribute(reinterpret_cast<const void*>(gemmt<1>),
                              hipFuncAttributeMaxDynamicSharedMemorySize, 73728);
    (void)hipFuncSetAttribute(reinterpret_cast<const void*>(gemmt<0>),
                              hipFuncAttributeMaxDynamicSharedMemorySize, 73728);

    prep_k<<<8448, 256, 0, stream>>>(x, wq, wk, wv, wo, WT, WoT, tab, xb);

    gemmt<1><<<dim3(12, 64), 256, 73728, stream>>>(xb, WT, Qb, Kb, Vt, tab,
                                                   (const unsigned short*)x);
    flash_k<<<dim3(64, 8), 512, 0, stream>>>(Qb, Kb, Vt, A2);
    gemmt<0><<<dim3(4, 64), 256, 73728, stream>>>(A2, WoT, d_out, nullptr, nullptr, tab,
                                                  (const unsigned short*)x);
}